// Round 1
// baseline (169.441 us; speedup 1.0000x reference)
//
#include <hip/hip_runtime.h>

// Problem geometry (fixed by reference): [16, 512, 512, 2] fp32, 41-tap separable gaussian.
#define NB   16
#define H    512
#define W    512
#define KW   41
#define HALO 20

// Tile: 64 x outputs, 52 y outputs per block, one (batch,channel) per blockIdx.z.
#define TX    64
#define TY    52
#define IN_W  (TX + 2*HALO)   // 104
#define IN_H  (TY + 2*HALO)   // 92
#define IN_WP (IN_W + 1)      // 105: stride pad -> <=2-way LDS bank aliasing (free)
#define MID_WP (TX + 1)       // 65
#define PV    (TY / 4)        // 13 outputs per thread in vertical pass

// Raw (unnormalized) gaussian taps exp(-d^2/50), d=-20..20. Normalization (1/sum)^2
// for the two passes is folded into INV_S2 applied once at the epilogue.
constexpr float G[KW] = {
  0.0003354626f, 0.0007318024f, 0.0015338104f, 0.0030887172f,
  0.0059760229f, 0.0111089965f, 0.0198410947f, 0.0340474548f,
  0.0561347628f, 0.0889216176f, 0.1353352832f, 0.1978986990f,
  0.2780373005f, 0.3753110988f, 0.4867522560f, 0.6065306597f,
  0.7261490371f, 0.8352702114f, 0.9231163464f, 0.9801986733f,
  1.0f,
  0.9801986733f, 0.9231163464f, 0.8352702114f, 0.7261490371f,
  0.6065306597f, 0.4867522560f, 0.3753110988f, 0.2780373005f,
  0.1978986990f, 0.1353352832f, 0.0889216176f, 0.0561347628f,
  0.0340474548f, 0.0198410947f, 0.0111089965f, 0.0059760229f,
  0.0030887172f, 0.0015338104f, 0.0007318024f, 0.0003354626f
};

constexpr float gsum() { float s = 0.f; for (int i = 0; i < KW; ++i) s += G[i]; return s; }
constexpr float INV_S2 = 1.0f / (gsum() * gsum());

__global__ __launch_bounds__(256, 2)
void randflow_blur_kernel(const float* __restrict__ noise, float* __restrict__ out) {
    __shared__ float s_in[IN_H][IN_WP];   // 92*105*4 = 38640 B
    __shared__ float s_mid[IN_H][MID_WP]; // 92*65*4  = 23920 B  (total 62560 B < 64 KB)

    const int tid = threadIdx.x;
    const int tx0 = blockIdx.x * TX;   // 8 tiles
    const int ty0 = blockIdx.y * TY;   // 10 tiles (covers 520, last rows guarded)
    const int bz  = blockIdx.z;        // b*2 + c
    const int b   = bz >> 1;
    const int c   = bz & 1;

    const float* __restrict__ src = noise + (size_t)b * (H * W * 2) + c;

    // ---- pass 0: global -> LDS input tile, flow = noise*2-1, zero pad outside image
    for (int i = tid; i < IN_H * IN_W; i += 256) {
        int r   = i / IN_W;
        int col = i - r * IN_W;
        int yin = ty0 + r   - HALO;
        int xin = tx0 + col - HALO;
        float v = 0.0f;
        if ((unsigned)yin < (unsigned)H && (unsigned)xin < (unsigned)W) {
            v = __builtin_fmaf(src[((size_t)yin * W + xin) * 2], 2.0f, -1.0f);
        }
        s_in[r][col] = v;
    }
    __syncthreads();

    // ---- pass 1: horizontal 41-tap conv -> s_mid. 8 outputs/thread sliding window:
    // 48 LDS reads per 8 outputs (6/output) instead of 41/output.
    for (int g0 = tid; g0 < IN_H * (TX / 8); g0 += 256) {
        int r   = g0 >> 3;
        int ox0 = (g0 & 7) << 3;
        float acc[8] = {0.f,0.f,0.f,0.f,0.f,0.f,0.f,0.f};
        #pragma unroll
        for (int j = 0; j < 8 + KW - 1; ++j) {
            float v = s_in[r][ox0 + j];
            #pragma unroll
            for (int p = 0; p < 8; ++p) {
                int t = j - p;                       // compile-time after unroll
                if (t >= 0 && t < KW)
                    acc[p] = __builtin_fmaf(G[t], v, acc[p]);
            }
        }
        #pragma unroll
        for (int p = 0; p < 8; ++p) s_mid[r][ox0 + p] = acc[p];
    }
    __syncthreads();

    // ---- pass 2: vertical 41-tap conv -> out. Each thread: one x column, PV=13
    // consecutive y outputs; 52 reads per 13 outputs (4/output). Reads conflict-free
    // (consecutive x across lanes).
    {
        const int x   = tid & 63;
        const int grp = tid >> 6;       // 0..3
        const int py0 = grp * PV;       // 0,13,26,39
        float acc[PV];
        #pragma unroll
        for (int p = 0; p < PV; ++p) acc[p] = 0.f;
        #pragma unroll
        for (int j = 0; j < PV + KW - 1; ++j) {     // 53 iters, row <= 39+52=91 = IN_H-1
            float v = s_mid[py0 + j][x];
            #pragma unroll
            for (int p = 0; p < PV; ++p) {
                int t = j - p;
                if (t >= 0 && t < KW)
                    acc[p] = __builtin_fmaf(G[t], v, acc[p]);
            }
        }
        const int xo = tx0 + x;
        #pragma unroll
        for (int p = 0; p < PV; ++p) {
            int yo = ty0 + py0 + p;
            if (yo < H) {
                out[(((size_t)b * H + yo) * W + xo) * 2 + c] = acc[p] * INV_S2;
            }
        }
    }
}

extern "C" void kernel_launch(void* const* d_in, const int* in_sizes, int n_in,
                              void* d_out, int out_size, void* d_ws, size_t ws_size,
                              hipStream_t stream) {
    // d_in[0] = inputs [16,512,512,1]  -- UNUSED by the reference
    // d_in[1] = rand_noise [16,512,512,2] fp32
    const float* noise = (const float*)d_in[1];
    float* out = (float*)d_out;

    dim3 grid(W / TX, (H + TY - 1) / TY, NB * 2);   // 8 x 10 x 32
    dim3 block(256);
    randflow_blur_kernel<<<grid, block, 0, stream>>>(noise, out);
}